// Round 4
// baseline (342.199 us; speedup 1.0000x reference)
//
#include <hip/hip_runtime.h>

typedef unsigned int uint;
typedef unsigned long long u64;

#define TD 20000
// ws layout in float units:
//  H:      [200][12][4]  = 9600 floats  (FIR taps: {e_s, i_s, e_ns, i_ns} per (k,s))
//  SPREAD: 2500 uint2    (5-bit-field spread masks: bit s of connectivity -> bit 5s)
//          entries 0..1999 = E neurons, 2000..2499 = I neurons
//  IN:     [20000][24]   (e counts in 0..11, i counts in 12..23)
//  SYN:    [20000][24]   (syn_s in 0..11, syn_ns in 12..23)
#define WS_H      0
#define WS_SPREAD 9600
#define WS_IN     14600
#define WS_SYN    494600

__device__ __forceinline__ float sigf(float x) { return 1.f / (1.f + __expf(-x)); }

// row_shr:k DPP add-scan within 16-lane rows; bound_ctrl=1 -> OOB reads 0.
__device__ __forceinline__ uint dpp_shr_add(uint v, const int ctrl_is /*1,2,4,8*/) {
  // dpp_ctrl row_shr:k = 0x110 | k
  switch (ctrl_is) {
    case 1: return v + (uint)__builtin_amdgcn_update_dpp(0, (int)v, 0x111, 0xf, 0xf, true);
    case 2: return v + (uint)__builtin_amdgcn_update_dpp(0, (int)v, 0x112, 0xf, 0xf, true);
    case 4: return v + (uint)__builtin_amdgcn_update_dpp(0, (int)v, 0x114, 0xf, 0xf, true);
    default: return v + (uint)__builtin_amdgcn_update_dpp(0, (int)v, 0x118, 0xf, 0xf, true);
  }
}

// ---------------- K1: FIR kernels + spread connectivity masks ----------------
__global__ __launch_bounds__(256) void k1_precomp(
    const float* __restrict__ Ce, const float* __restrict__ Ci,
    const float* __restrict__ Wsy_s, const float* __restrict__ Wsy_ns,
    const float* __restrict__ Del_s, const float* __restrict__ Del_ns,
    float* __restrict__ ws) {
  int p = blockIdx.x * 256 + threadIdx.x;
  if (p < 2400) {
    int k = p / 12, s = p - (p / 12) * 12;
    float o[4];
    for (int ch = 0; ch < 2; ++ch) {
      const float* W = ch ? Wsy_ns : Wsy_s;
      const float* D = ch ? Del_ns : Del_s;
      for (int c = 0; c < 2; ++c) {
        float ts = fmaxf((float)k - __expf(D[s * 2 + c]), 0.f);
        float v = 0.f;
        for (int b = 0; b < 3; ++b) {
          float tt = ts * __expf(-0.5f * (float)b);
          v += W[s * 6 + b * 2 + c] * tt * __expf(-tt);
        }
        o[ch * 2 + c] = v;
      }
    }
    float* H = ws + WS_H + (size_t)(k * 12 + s) * 4;
    H[0] = o[0]; H[1] = o[1]; H[2] = o[2]; H[3] = o[3];
  }
  int q = p - 2400;
  if (q >= 0 && q < 2500) {
    uint m = 0;
    if (q < 2000) {
      for (int s = 0; s < 12; ++s) m |= (Ce[s * 2000 + q] != 0.f ? (1u << s) : 0u);
    } else {
      int e = q - 2000;
      for (int s = 0; s < 12; ++s) m |= (Ci[s * 500 + e] != 0.f ? (1u << s) : 0u);
    }
    u64 sp = 0ull;
    for (int s = 0; s < 12; ++s) sp |= (u64)((m >> s) & 1u) << (5 * s);
    ((uint2*)(ws + WS_SPREAD))[q] = make_uint2((uint)sp, (uint)(sp >> 32));
  }
}

// ---------------- K2: IN = S @ C^T via spread-mask accumulation ----------------
// v3: 4 rows per wave, 16 lanes per row. Masks from global (20 KB, L1-resident;
// rows 1-3 broadcast row 0's addresses). Reduction = 4 DPP row_shr add-scans
// (pure VALU, zero LDS-pipe usage; kernel uses no LDS at all). Integer-exact:
// 5-bit fields flushed every 4 float4s (<=16 per field), packed E|I<<16 totals
// <=500 per half.
__global__ __launch_bounds__(256) void k2_project(
    const float* __restrict__ Se, const float* __restrict__ Si,
    float* __restrict__ ws) {
  const int lane = threadIdx.x & 63;
  const int wv = blockIdx.x * 4 + (threadIdx.x >> 6);  // 5000 waves
  const int r = lane >> 4;        // row within wave
  const int c = lane & 15;        // column lane within row
  const int t = wv * 4 + r;
  const uint4* SP4 = (const uint4*)(ws + WS_SPREAD);
  float* INb = ws + WS_IN;

  uint eTot[12];
#pragma unroll
  for (int s = 0; s < 12; ++s) eTot[s] = 0u;
  u64 acc = 0ull;
  const float4* Sr = (const float4*)(Se + (size_t)t * 2000);
#pragma unroll
  for (int it = 0; it < 32; ++it) {
    int i4 = c + it * 16;
    if (i4 < 500) {
      float4 sv = Sr[i4];
      uint4 a = SP4[2 * i4];
      uint4 b = SP4[2 * i4 + 1];
      u64 m0 = (u64)a.x | ((u64)a.y << 32);
      u64 m1 = (u64)a.z | ((u64)a.w << 32);
      u64 m2 = (u64)b.x | ((u64)b.y << 32);
      u64 m3 = (u64)b.z | ((u64)b.w << 32);
      acc += (sv.x != 0.f ? m0 : 0ull);
      acc += (sv.y != 0.f ? m1 : 0ull);
      acc += (sv.z != 0.f ? m2 : 0ull);
      acc += (sv.w != 0.f ? m3 : 0ull);
    }
    if ((it & 3) == 3) {
#pragma unroll
      for (int s = 0; s < 12; ++s) eTot[s] += (uint)(acc >> (5 * s)) & 31u;
      acc = 0ull;
    }
  }
  // ----- I channel: 125 float4s over 16 lanes, flush at halfway -----
  uint iTot[12];
#pragma unroll
  for (int s = 0; s < 12; ++s) iTot[s] = 0u;
  u64 accI = 0ull;
  const float4* Sir = (const float4*)(Si + (size_t)t * 500);
#pragma unroll
  for (int it = 0; it < 8; ++it) {
    int i4 = c + it * 16;
    if (i4 < 125) {
      float4 sv = Sir[i4];
      uint4 a = SP4[1000 + 2 * i4];
      uint4 b = SP4[1000 + 2 * i4 + 1];
      u64 m0 = (u64)a.x | ((u64)a.y << 32);
      u64 m1 = (u64)a.z | ((u64)a.w << 32);
      u64 m2 = (u64)b.x | ((u64)b.y << 32);
      u64 m3 = (u64)b.z | ((u64)b.w << 32);
      accI += (sv.x != 0.f ? m0 : 0ull);
      accI += (sv.y != 0.f ? m1 : 0ull);
      accI += (sv.z != 0.f ? m2 : 0ull);
      accI += (sv.w != 0.f ? m3 : 0ull);
    }
    if (it == 3) {
#pragma unroll
      for (int s = 0; s < 12; ++s) iTot[s] += (uint)(accI >> (5 * s)) & 31u;
      accI = 0ull;
    }
  }
#pragma unroll
  for (int s = 0; s < 12; ++s) iTot[s] += (uint)(accI >> (5 * s)) & 31u;

  uint pk[12];
#pragma unroll
  for (int s = 0; s < 12; ++s) pk[s] = eTot[s] | (iTot[s] << 16);
  // DPP add-scan within each 16-lane row; lane c==15 holds the row total.
#pragma unroll
  for (int s = 0; s < 12; ++s) {
    uint v = pk[s];
    v = dpp_shr_add(v, 1);
    v = dpp_shr_add(v, 2);
    v = dpp_shr_add(v, 4);
    v = dpp_shr_add(v, 8);
    pk[s] = v;
  }
  if (c == 15) {
    float4* o = (float4*)(INb + (size_t)t * 24);
    o[0] = make_float4((float)(pk[0] & 0xffffu), (float)(pk[1] & 0xffffu),
                       (float)(pk[2] & 0xffffu), (float)(pk[3] & 0xffffu));
    o[1] = make_float4((float)(pk[4] & 0xffffu), (float)(pk[5] & 0xffffu),
                       (float)(pk[6] & 0xffffu), (float)(pk[7] & 0xffffu));
    o[2] = make_float4((float)(pk[8] & 0xffffu), (float)(pk[9] & 0xffffu),
                       (float)(pk[10] & 0xffffu), (float)(pk[11] & 0xffffu));
    o[3] = make_float4((float)(pk[0] >> 16), (float)(pk[1] >> 16),
                       (float)(pk[2] >> 16), (float)(pk[3] >> 16));
    o[4] = make_float4((float)(pk[4] >> 16), (float)(pk[5] >> 16),
                       (float)(pk[6] >> 16), (float)(pk[7] >> 16));
    o[5] = make_float4((float)(pk[8] >> 16), (float)(pk[9] >> 16),
                       (float)(pk[10] >> 16), (float)(pk[11] >> 16));
  }
}

// ---------------- K3: causal FIR, K=200, s-group split across blockIdx.y ----------------
// block = 64 t's x 3 subunits (both channels); 4 waves split the 200 taps.
// red[] row stride 7 (gcd(7,32)=1 -> conflict-free).
__global__ __launch_bounds__(256) void k3_conv(float* __restrict__ ws) {
  __shared__ float tile[6 * 264];
  __shared__ float red[4 * 64 * 7];
  const int g = blockIdx.y;        // subunit group: s in [3g, 3g+3)
  const int t0 = blockIdx.x * 64;
  const float* INb = ws + WS_IN;
  for (int p = threadIdx.x; p < 263 * 6; p += 256) {
    int row = p / 6, c = p - row * 6;
    int ch = (c < 3) ? (3 * g + c) : (9 + 3 * g + c);  // e: 3g+c ; i: 12+3g+(c-3)
    int gt = t0 - 199 + row;
    tile[c * 264 + row] = (gt >= 0 && gt < TD) ? INb[(size_t)gt * 24 + ch] : 0.f;
  }
  __syncthreads();
  const int lane = threadIdx.x & 63;
  const int q = threadIdx.x >> 6;
  const float4* H4 = (const float4*)(ws + WS_H);
  float accs[3] = {0.f, 0.f, 0.f}, accn[3] = {0.f, 0.f, 0.f};
  for (int kk = 0; kk < 25; ++kk) {
    int k = q * 50 + kk * 2;      // taps k and k+1
    int rb = lane + 198 - k;      // LDS row of tap k+1 (tap k at rb+1)
#pragma unroll
    for (int s = 0; s < 3; ++s) {
      float ve0 = tile[s * 264 + rb];
      float ve1 = tile[s * 264 + rb + 1];
      float vi0 = tile[(3 + s) * 264 + rb];
      float vi1 = tile[(3 + s) * 264 + rb + 1];
      float4 h0 = H4[k * 12 + 3 * g + s];
      float4 h1 = H4[(k + 1) * 12 + 3 * g + s];
      accs[s] += h0.x * ve1 + h0.y * vi1 + h1.x * ve0 + h1.y * vi0;
      accn[s] += h0.z * ve1 + h0.w * vi1 + h1.z * ve0 + h1.w * vi0;
    }
  }
  float* mr = red + (q * 64 + lane) * 7;
#pragma unroll
  for (int s = 0; s < 3; ++s) { mr[s] = accs[s]; mr[3 + s] = accn[s]; }
  __syncthreads();
  for (int p = threadIdx.x; p < 64 * 6; p += 256) {
    int row = p / 6, c = p - row * 6;
    if (t0 + row < TD) {
      float sum = red[row * 7 + c] + red[(64 + row) * 7 + c] +
                  red[(128 + row) * 7 + c] + red[(192 + row) * 7 + c];
      int ch = (c < 3) ? (3 * g + c) : (9 + 3 * g + c);
      ws[WS_SYN + (size_t)(t0 + row) * 24 + ch] = sum;
    }
  }
}

// ---------------- K45: one thread per t. C_den strictly lower-tri => nilpotent
// => bounded influence horizon; 13-step warm-up makes A[t-1] and A[t] exact.
// s-chain is non-recurrent given A[t-1] (B[t-1][0] is closed-form). ----------------
__global__ void k45_out(
    const float* __restrict__ Cden, const float* __restrict__ Ws_sub,
    const float* __restrict__ Wns_sub, const float* __restrict__ Th_s,
    const float* __restrict__ Th_ns, const float* __restrict__ ws,
    float* __restrict__ out) {
  __shared__ float lout[64 * 35];
  const int t = blockIdx.x * 64 + threadIdx.x;
  float v[35];
#pragma unroll
  for (int m = 0; m < 35; ++m) v[m] = 0.f;
  if (t < TD) {
    const float* SYN = ws + WS_SYN;
    float dns[12][12];
#pragma unroll
    for (int i = 1; i < 12; ++i)
#pragma unroll
      for (int j = 0; j < i; ++j) dns[i][j] = Cden[i * 12 + j] * Wns_sub[j];
    float th[12];
#pragma unroll
    for (int i = 0; i < 12; ++i) th[i] = Th_ns[i];
    float ap[12], an[12];
#pragma unroll
    for (int i = 0; i < 12; ++i) { ap[i] = 0.f; an[i] = 0.f; }
    int start = t - 12; if (start < 0) start = 0;
    for (int tau = start; tau <= t; ++tau) {
      const float4* sr = (const float4*)(SYN + (size_t)tau * 24 + 12);
      float4 s0 = sr[0], s1 = sr[1], s2 = sr[2];
      float sn[12] = {s0.x, s0.y, s0.z, s0.w, s1.x, s1.y, s1.z, s1.w,
                      s2.x, s2.y, s2.z, s2.w};
#pragma unroll
      for (int i = 0; i < 12; ++i) {
        float x = sn[i] + th[i];
#pragma unroll
        for (int j = 0; j < i; ++j) x += dns[i][j] * ap[j];
        an[i] = sigf(x);
      }
      if (tau < t) {
#pragma unroll
        for (int i = 0; i < 12; ++i) ap[i] = an[i];
      }
    }
    // an = A[t], ap = A[t-1] (zeros if t==0)
    float sns[12];
    {
      const float4* sr = (const float4*)(SYN + (size_t)t * 24);
      float4 s0 = sr[0], s1 = sr[1], s2 = sr[2];
      sns[0] = s0.x; sns[1] = s0.y; sns[2] = s0.z; sns[3] = s0.w;
      sns[4] = s1.x; sns[5] = s1.y; sns[6] = s1.z; sns[7] = s1.w;
      sns[8] = s2.x; sns[9] = s2.y; sns[10] = s2.z; sns[11] = s2.w;
    }
    float carry[12];
    carry[0] = (t > 0) ? Ws_sub[0] * sigf(SYN[(size_t)(t - 1) * 24] + Th_s[0]) : 0.f;
#pragma unroll
    for (int j = 1; j < 12; ++j) carry[j] = Ws_sub[j] * ap[j];
    float B[12];
#pragma unroll
    for (int i = 0; i < 12; ++i) {
      float x = sns[i] + Th_s[i];
#pragma unroll
      for (int j = 0; j < i; ++j) x += Cden[i * 12 + j] * carry[j];
      B[i] = sigf(x);
    }
    v[0] = B[0] * Ws_sub[0];
#pragma unroll
    for (int i = 1; i < 12; ++i) v[i] = an[i] * Ws_sub[i];
#pragma unroll
    for (int i = 0; i < 12; ++i) v[12 + i] = an[i] * Wns_sub[i];
#pragma unroll
    for (int i = 1; i < 12; ++i) v[23 + i] = B[i];
  }
#pragma unroll
  for (int m = 0; m < 35; ++m) lout[threadIdx.x * 35 + m] = v[m];
  __syncthreads();
  const int t0 = blockIdx.x * 64;
  int nrow = TD - t0; if (nrow > 64) nrow = 64;
  const int valid = nrow * 35;
  for (int p = threadIdx.x; p < valid; p += 64) out[(size_t)t0 * 35 + p] = lout[p];
}

extern "C" void kernel_launch(void* const* d_in, const int* in_sizes, int n_in,
                              void* d_out, int out_size, void* d_ws, size_t ws_size,
                              hipStream_t stream) {
  const float* Se = (const float*)d_in[0];
  const float* Si = (const float*)d_in[1];
  const float* Ce = (const float*)d_in[2];
  const float* Ci = (const float*)d_in[3];
  const float* Cden = (const float*)d_in[4];
  const float* Wsy_s = (const float*)d_in[5];
  const float* Wsy_ns = (const float*)d_in[6];
  const float* Del_s = (const float*)d_in[7];
  const float* Del_ns = (const float*)d_in[8];
  const float* Th_s = (const float*)d_in[9];
  const float* Th_ns = (const float*)d_in[10];
  const float* Ws_sub = (const float*)d_in[11];
  const float* Wns_sub = (const float*)d_in[12];
  // d_in[13..16] (hist/prop weights) multiply an identically-zero history buffer.
  float* ws = (float*)d_ws;
  float* out = (float*)d_out;

  k1_precomp<<<20, 256, 0, stream>>>(Ce, Ci, Wsy_s, Wsy_ns, Del_s, Del_ns, ws);
  k2_project<<<1250, 256, 0, stream>>>(Se, Si, ws);
  dim3 g3(313, 4);
  k3_conv<<<g3, 256, 0, stream>>>(ws);
  k45_out<<<313, 64, 0, stream>>>(Cden, Ws_sub, Wns_sub, Th_s, Th_ns, ws, out);
}

// Round 5
// 330.269 us; speedup vs baseline: 1.0361x; 1.0361x over previous
//
#include <hip/hip_runtime.h>

typedef unsigned int uint;
typedef unsigned long long u64;

#define TD 20000
// ws layout in float units:
//  H:      [200][12][4]  = 9600 floats  (FIR taps: {e_s, i_s, e_ns, i_ns} per (k,s))
//  SPREAD: 2500 uint2    (5-bit-field spread masks: bit s of connectivity -> bit 5s)
//          entries 0..1999 = E neurons, 2000..2499 = I neurons
//  IN:     [20000][24]   (e counts in 0..11, i counts in 12..23)
//  SYN:    [20000][24]   (syn_s in 0..11, syn_ns in 12..23)
#define WS_H      0
#define WS_SPREAD 9600
#define WS_IN     14600
#define WS_SYN    494600

__device__ __forceinline__ float sigf(float x) { return 1.f / (1.f + __expf(-x)); }

// ---------------- K1: FIR kernels + spread connectivity masks ----------------
__global__ __launch_bounds__(256) void k1_precomp(
    const float* __restrict__ Ce, const float* __restrict__ Ci,
    const float* __restrict__ Wsy_s, const float* __restrict__ Wsy_ns,
    const float* __restrict__ Del_s, const float* __restrict__ Del_ns,
    float* __restrict__ ws) {
  int p = blockIdx.x * 256 + threadIdx.x;
  if (p < 2400) {
    int k = p / 12, s = p - (p / 12) * 12;
    float o[4];
    for (int ch = 0; ch < 2; ++ch) {
      const float* W = ch ? Wsy_ns : Wsy_s;
      const float* D = ch ? Del_ns : Del_s;
      for (int c = 0; c < 2; ++c) {
        float ts = fmaxf((float)k - __expf(D[s * 2 + c]), 0.f);
        float v = 0.f;
        for (int b = 0; b < 3; ++b) {
          float tt = ts * __expf(-0.5f * (float)b);
          v += W[s * 6 + b * 2 + c] * tt * __expf(-tt);
        }
        o[ch * 2 + c] = v;
      }
    }
    float* H = ws + WS_H + (size_t)(k * 12 + s) * 4;
    H[0] = o[0]; H[1] = o[1]; H[2] = o[2]; H[3] = o[3];
  }
  int q = p - 2400;
  if (q >= 0 && q < 2500) {
    uint m = 0;
    if (q < 2000) {
      for (int s = 0; s < 12; ++s) m |= (Ce[s * 2000 + q] != 0.f ? (1u << s) : 0u);
    } else {
      int e = q - 2000;
      for (int s = 0; s < 12; ++s) m |= (Ci[s * 500 + e] != 0.f ? (1u << s) : 0u);
    }
    u64 sp = 0ull;
    for (int s = 0; s < 12; ++s) sp |= (u64)((m >> s) & 1u) << (5 * s);
    ((uint2*)(ws + WS_SPREAD))[q] = make_uint2((uint)sp, (uint)(sp >> 32));
  }
}

// ---------------- K2: IN = S @ C^T via spread-mask accumulation ----------------
// v4 = R3 structure (1 row/wave, 64 lanes, LDS masks, shfl_xor reduce) with
// maximum memory-level parallelism: all 10 global float4 loads issue
// unconditionally up-front (tail lanes take a zeroed value, masks padded so
// OOB LDS reads are harmless). VGPR target < 128.
__global__ __launch_bounds__(256) void k2_project(
    const float* __restrict__ Se, const float* __restrict__ Si,
    float* __restrict__ ws) {
  __shared__ __align__(16) uint2 sp[2520];  // 20 entries of pad for tail lanes
  {
    const uint2* g = (const uint2*)(ws + WS_SPREAD);
    for (int p = threadIdx.x; p < 2500; p += 256) sp[p] = g[p];
    if (threadIdx.x < 20) sp[2500 + threadIdx.x] = make_uint2(0u, 0u);
  }
  __syncthreads();
  const int lane = threadIdx.x & 63;
  const int t = blockIdx.x * 4 + (threadIdx.x >> 6);  // one time-row per wave
  const uint4* SP4 = (const uint4*)sp;
  float* INb = ws + WS_IN;

  // ---- issue ALL global loads first (7 full + 1 tail E, 1 full + 1 tail I) ----
  const float4 z4 = make_float4(0.f, 0.f, 0.f, 0.f);
  const float4* Sr = (const float4*)(Se + (size_t)t * 2000);
  const float4* Sir = (const float4*)(Si + (size_t)t * 500);
  float4 sv[8];
#pragma unroll
  for (int it = 0; it < 7; ++it) sv[it] = Sr[lane + it * 64];
  sv[7] = (lane < 52) ? Sr[448 + lane] : z4;     // i4 in [448,500)
  float4 si0 = Sir[lane];                        // i4 in [0,64) < 125
  float4 si1 = (lane < 61) ? Sir[64 + lane] : z4;  // i4 in [64,125)

  // ---- E channel: flush 5-bit fields after 4 float4s (max 16 < 31) ----
  uint eTot[12];
#pragma unroll
  for (int s = 0; s < 12; ++s) eTot[s] = 0u;
  u64 acc = 0ull;
#pragma unroll
  for (int it = 0; it < 8; ++it) {
    int i4 = lane + it * 64;  // <= 511; mask pad covers OOB (spike=0 anyway)
    uint4 a = SP4[2 * i4];
    uint4 b = SP4[2 * i4 + 1];
    u64 m0 = (u64)a.x | ((u64)a.y << 32);
    u64 m1 = (u64)a.z | ((u64)a.w << 32);
    u64 m2 = (u64)b.x | ((u64)b.y << 32);
    u64 m3 = (u64)b.z | ((u64)b.w << 32);
    acc += (sv[it].x != 0.f ? m0 : 0ull);
    acc += (sv[it].y != 0.f ? m1 : 0ull);
    acc += (sv[it].z != 0.f ? m2 : 0ull);
    acc += (sv[it].w != 0.f ? m3 : 0ull);
    if (it == 3) {
#pragma unroll
      for (int s = 0; s < 12; ++s) eTot[s] += (uint)(acc >> (5 * s)) & 31u;
      acc = 0ull;
    }
  }
#pragma unroll
  for (int s = 0; s < 12; ++s) eTot[s] += (uint)(acc >> (5 * s)) & 31u;

  // ---- I channel: max 8 adds per field, no flush needed ----
  u64 accI = 0ull;
  {
    int i4 = lane;
    uint4 a = SP4[1000 + 2 * i4];
    uint4 b = SP4[1000 + 2 * i4 + 1];
    accI += (si0.x != 0.f ? ((u64)a.x | ((u64)a.y << 32)) : 0ull);
    accI += (si0.y != 0.f ? ((u64)a.z | ((u64)a.w << 32)) : 0ull);
    accI += (si0.z != 0.f ? ((u64)b.x | ((u64)b.y << 32)) : 0ull);
    accI += (si0.w != 0.f ? ((u64)b.z | ((u64)b.w << 32)) : 0ull);
    i4 = 64 + lane;  // <= 127; pad covers 125..127 (spike=0 anyway)
    uint4 c = SP4[1000 + 2 * i4];
    uint4 d = SP4[1000 + 2 * i4 + 1];
    accI += (si1.x != 0.f ? ((u64)c.x | ((u64)c.y << 32)) : 0ull);
    accI += (si1.y != 0.f ? ((u64)c.z | ((u64)c.w << 32)) : 0ull);
    accI += (si1.z != 0.f ? ((u64)d.x | ((u64)d.y << 32)) : 0ull);
    accI += (si1.w != 0.f ? ((u64)d.z | ((u64)d.w << 32)) : 0ull);
  }

  uint pk[12];
#pragma unroll
  for (int s = 0; s < 12; ++s)
    pk[s] = eTot[s] | (((uint)(accI >> (5 * s)) & 31u) << 16);
#pragma unroll
  for (int s = 0; s < 12; ++s) {
    uint v = pk[s];
    v += __shfl_xor(v, 32, 64);
    v += __shfl_xor(v, 16, 64);
    v += __shfl_xor(v, 8, 64);
    v += __shfl_xor(v, 4, 64);
    v += __shfl_xor(v, 2, 64);
    v += __shfl_xor(v, 1, 64);
    pk[s] = v;
  }
  if (lane == 0) {
    float4* o = (float4*)(INb + (size_t)t * 24);
    o[0] = make_float4((float)(pk[0] & 0xffffu), (float)(pk[1] & 0xffffu),
                       (float)(pk[2] & 0xffffu), (float)(pk[3] & 0xffffu));
    o[1] = make_float4((float)(pk[4] & 0xffffu), (float)(pk[5] & 0xffffu),
                       (float)(pk[6] & 0xffffu), (float)(pk[7] & 0xffffu));
    o[2] = make_float4((float)(pk[8] & 0xffffu), (float)(pk[9] & 0xffffu),
                       (float)(pk[10] & 0xffffu), (float)(pk[11] & 0xffffu));
    o[3] = make_float4((float)(pk[0] >> 16), (float)(pk[1] >> 16),
                       (float)(pk[2] >> 16), (float)(pk[3] >> 16));
    o[4] = make_float4((float)(pk[4] >> 16), (float)(pk[5] >> 16),
                       (float)(pk[6] >> 16), (float)(pk[7] >> 16));
    o[5] = make_float4((float)(pk[8] >> 16), (float)(pk[9] >> 16),
                       (float)(pk[10] >> 16), (float)(pk[11] >> 16));
  }
}

// ---------------- K3: causal FIR, K=200, s-group split across blockIdx.y ----------------
// block = 64 t's x 3 subunits (both channels); 4 waves split the 200 taps.
// red[] row stride 7 (gcd(7,32)=1 -> conflict-free).
__global__ __launch_bounds__(256) void k3_conv(float* __restrict__ ws) {
  __shared__ float tile[6 * 264];
  __shared__ float red[4 * 64 * 7];
  const int g = blockIdx.y;        // subunit group: s in [3g, 3g+3)
  const int t0 = blockIdx.x * 64;
  const float* INb = ws + WS_IN;
  for (int p = threadIdx.x; p < 263 * 6; p += 256) {
    int row = p / 6, c = p - row * 6;
    int ch = (c < 3) ? (3 * g + c) : (9 + 3 * g + c);  // e: 3g+c ; i: 12+3g+(c-3)
    int gt = t0 - 199 + row;
    tile[c * 264 + row] = (gt >= 0 && gt < TD) ? INb[(size_t)gt * 24 + ch] : 0.f;
  }
  __syncthreads();
  const int lane = threadIdx.x & 63;
  const int q = threadIdx.x >> 6;
  const float4* H4 = (const float4*)(ws + WS_H);
  float accs[3] = {0.f, 0.f, 0.f}, accn[3] = {0.f, 0.f, 0.f};
  for (int kk = 0; kk < 25; ++kk) {
    int k = q * 50 + kk * 2;      // taps k and k+1
    int rb = lane + 198 - k;      // LDS row of tap k+1 (tap k at rb+1)
#pragma unroll
    for (int s = 0; s < 3; ++s) {
      float ve0 = tile[s * 264 + rb];
      float ve1 = tile[s * 264 + rb + 1];
      float vi0 = tile[(3 + s) * 264 + rb];
      float vi1 = tile[(3 + s) * 264 + rb + 1];
      float4 h0 = H4[k * 12 + 3 * g + s];
      float4 h1 = H4[(k + 1) * 12 + 3 * g + s];
      accs[s] += h0.x * ve1 + h0.y * vi1 + h1.x * ve0 + h1.y * vi0;
      accn[s] += h0.z * ve1 + h0.w * vi1 + h1.z * ve0 + h1.w * vi0;
    }
  }
  float* mr = red + (q * 64 + lane) * 7;
#pragma unroll
  for (int s = 0; s < 3; ++s) { mr[s] = accs[s]; mr[3 + s] = accn[s]; }
  __syncthreads();
  for (int p = threadIdx.x; p < 64 * 6; p += 256) {
    int row = p / 6, c = p - row * 6;
    if (t0 + row < TD) {
      float sum = red[row * 7 + c] + red[(64 + row) * 7 + c] +
                  red[(128 + row) * 7 + c] + red[(192 + row) * 7 + c];
      int ch = (c < 3) ? (3 * g + c) : (9 + 3 * g + c);
      ws[WS_SYN + (size_t)(t0 + row) * 24 + ch] = sum;
    }
  }
}

// ---------------- K45: one thread per t. C_den strictly lower-tri => nilpotent
// => bounded influence horizon; 13-step warm-up makes A[t-1] and A[t] exact.
// s-chain is non-recurrent given A[t-1] (B[t-1][0] is closed-form). ----------------
__global__ void k45_out(
    const float* __restrict__ Cden, const float* __restrict__ Ws_sub,
    const float* __restrict__ Wns_sub, const float* __restrict__ Th_s,
    const float* __restrict__ Th_ns, const float* __restrict__ ws,
    float* __restrict__ out) {
  __shared__ float lout[64 * 35];
  const int t = blockIdx.x * 64 + threadIdx.x;
  float v[35];
#pragma unroll
  for (int m = 0; m < 35; ++m) v[m] = 0.f;
  if (t < TD) {
    const float* SYN = ws + WS_SYN;
    float dns[12][12];
#pragma unroll
    for (int i = 1; i < 12; ++i)
#pragma unroll
      for (int j = 0; j < i; ++j) dns[i][j] = Cden[i * 12 + j] * Wns_sub[j];
    float th[12];
#pragma unroll
    for (int i = 0; i < 12; ++i) th[i] = Th_ns[i];
    float ap[12], an[12];
#pragma unroll
    for (int i = 0; i < 12; ++i) { ap[i] = 0.f; an[i] = 0.f; }
    int start = t - 12; if (start < 0) start = 0;
    for (int tau = start; tau <= t; ++tau) {
      const float4* sr = (const float4*)(SYN + (size_t)tau * 24 + 12);
      float4 s0 = sr[0], s1 = sr[1], s2 = sr[2];
      float sn[12] = {s0.x, s0.y, s0.z, s0.w, s1.x, s1.y, s1.z, s1.w,
                      s2.x, s2.y, s2.z, s2.w};
#pragma unroll
      for (int i = 0; i < 12; ++i) {
        float x = sn[i] + th[i];
#pragma unroll
        for (int j = 0; j < i; ++j) x += dns[i][j] * ap[j];
        an[i] = sigf(x);
      }
      if (tau < t) {
#pragma unroll
        for (int i = 0; i < 12; ++i) ap[i] = an[i];
      }
    }
    // an = A[t], ap = A[t-1] (zeros if t==0)
    float sns[12];
    {
      const float4* sr = (const float4*)(SYN + (size_t)t * 24);
      float4 s0 = sr[0], s1 = sr[1], s2 = sr[2];
      sns[0] = s0.x; sns[1] = s0.y; sns[2] = s0.z; sns[3] = s0.w;
      sns[4] = s1.x; sns[5] = s1.y; sns[6] = s1.z; sns[7] = s1.w;
      sns[8] = s2.x; sns[9] = s2.y; sns[10] = s2.z; sns[11] = s2.w;
    }
    float carry[12];
    carry[0] = (t > 0) ? Ws_sub[0] * sigf(SYN[(size_t)(t - 1) * 24] + Th_s[0]) : 0.f;
#pragma unroll
    for (int j = 1; j < 12; ++j) carry[j] = Ws_sub[j] * ap[j];
    float B[12];
#pragma unroll
    for (int i = 0; i < 12; ++i) {
      float x = sns[i] + Th_s[i];
#pragma unroll
      for (int j = 0; j < i; ++j) x += Cden[i * 12 + j] * carry[j];
      B[i] = sigf(x);
    }
    v[0] = B[0] * Ws_sub[0];
#pragma unroll
    for (int i = 1; i < 12; ++i) v[i] = an[i] * Ws_sub[i];
#pragma unroll
    for (int i = 0; i < 12; ++i) v[12 + i] = an[i] * Wns_sub[i];
#pragma unroll
    for (int i = 1; i < 12; ++i) v[23 + i] = B[i];
  }
#pragma unroll
  for (int m = 0; m < 35; ++m) lout[threadIdx.x * 35 + m] = v[m];
  __syncthreads();
  const int t0 = blockIdx.x * 64;
  int nrow = TD - t0; if (nrow > 64) nrow = 64;
  const int valid = nrow * 35;
  for (int p = threadIdx.x; p < valid; p += 64) out[(size_t)t0 * 35 + p] = lout[p];
}

extern "C" void kernel_launch(void* const* d_in, const int* in_sizes, int n_in,
                              void* d_out, int out_size, void* d_ws, size_t ws_size,
                              hipStream_t stream) {
  const float* Se = (const float*)d_in[0];
  const float* Si = (const float*)d_in[1];
  const float* Ce = (const float*)d_in[2];
  const float* Ci = (const float*)d_in[3];
  const float* Cden = (const float*)d_in[4];
  const float* Wsy_s = (const float*)d_in[5];
  const float* Wsy_ns = (const float*)d_in[6];
  const float* Del_s = (const float*)d_in[7];
  const float* Del_ns = (const float*)d_in[8];
  const float* Th_s = (const float*)d_in[9];
  const float* Th_ns = (const float*)d_in[10];
  const float* Ws_sub = (const float*)d_in[11];
  const float* Wns_sub = (const float*)d_in[12];
  // d_in[13..16] (hist/prop weights) multiply an identically-zero history buffer.
  float* ws = (float*)d_ws;
  float* out = (float*)d_out;

  k1_precomp<<<20, 256, 0, stream>>>(Ce, Ci, Wsy_s, Wsy_ns, Del_s, Del_ns, ws);
  k2_project<<<5000, 256, 0, stream>>>(Se, Si, ws);
  dim3 g3(313, 4);
  k3_conv<<<g3, 256, 0, stream>>>(ws);
  k45_out<<<313, 64, 0, stream>>>(Cden, Ws_sub, Wns_sub, Th_s, Th_ns, ws, out);
}